// Round 3
// baseline (322.509 us; speedup 1.0000x reference)
//
#include <hip/hip_runtime.h>

#define N 8192
#define D 256
#define JSPLIT 16
#define NEG_INF (-__builtin_inff())

typedef __bf16 bf16x8 __attribute__((ext_vector_type(8)));
typedef float f32x4 __attribute__((ext_vector_type(4)));

// async global->LDS, 16 bytes/lane; LDS dest is wave-uniform base + lane*16
__device__ __forceinline__ void gload16(const void* g, void* lds) {
    __builtin_amdgcn_global_load_lds(
        (const __attribute__((address_space(1))) void*)g,
        (__attribute__((address_space(3))) void*)lds, 16, 0, 0);
}

__device__ __forceinline__ unsigned short f2bf(float f) {
    unsigned int u = __float_as_uint(f);
    unsigned int r = (u + 0x7FFFu + ((u >> 16) & 1u)) >> 16;  // RNE
    return (unsigned short)r;
}
__device__ __forceinline__ float bf2f(unsigned short b) {
    return __uint_as_float(((unsigned int)b) << 16);
}

// ---------------------------------------------------------------- kernel 0
// Fused: split-bf16 decompose (qh = bf16(q), ql = bf16(q - qh)) + row norms.
// One wave per row (64 lanes x float4 = D).
__global__ __launch_bounds__(256) void prep_kernel(const float* __restrict__ q,
                                                   unsigned short* __restrict__ qh,
                                                   unsigned short* __restrict__ ql,
                                                   float* __restrict__ sq) {
    const int row = blockIdx.x * 4 + (threadIdx.x >> 6);
    const int lane = threadIdx.x & 63;
    const float4 v = ((const float4*)(q + row * D))[lane];
    ushort4 h, l;
    h.x = f2bf(v.x); l.x = f2bf(v.x - bf2f(h.x));
    h.y = f2bf(v.y); l.y = f2bf(v.y - bf2f(h.y));
    h.z = f2bf(v.z); l.z = f2bf(v.z - bf2f(h.z));
    h.w = f2bf(v.w); l.w = f2bf(v.w - bf2f(h.w));
    ((ushort4*)(qh + row * D))[lane] = h;
    ((ushort4*)(ql + row * D))[lane] = l;
    float s = v.x * v.x + v.y * v.y + v.z * v.z + v.w * v.w;
    #pragma unroll
    for (int off = 32; off; off >>= 1) s += __shfl_down(s, off, 64);
    if (lane == 0) sq[row] = s;
}

// ---------------------------------------------------------------- kernel 1
// MFMA split-bf16 miner. Block: 256 threads = 2x2 waves, 128x128 output tile,
// each wave 64x64 via 4x4 frags of 16x16x32. Grid (N/128, JSPLIT) = 1024
// blocks = 4 resident blocks/CU (VGPR<=128, LDS 34.8KB). Each block scans
// 64/JSPLIT j-tiles, per-row running argmax state in LDS.
__global__ __launch_bounds__(256) void mine_kernel(
    const unsigned short* __restrict__ qh, const unsigned short* __restrict__ ql,
    const int* __restrict__ tgt, const float* __restrict__ sqv,
    float* __restrict__ pos_val, int* __restrict__ pos_idx,
    float* __restrict__ neg_val, int* __restrict__ neg_idx)
{
    __shared__ unsigned short Ah[128 * 32], Al[128 * 32];
    __shared__ unsigned short Bh[128 * 32], Bl[128 * 32];
    __shared__ float bpvS[128], bnvS[128];
    __shared__ int   bpiS[128], bniS[128];

    const int i0 = blockIdx.x * 128;
    const int jsplit = blockIdx.y;

    const int tid = threadIdx.x;
    const int w = tid >> 6, lane = tid & 63;
    const int quad = lane >> 4, lc = lane & 15;
    const int wy = w >> 1, wx = w & 1;

    if (tid < 128) {
        bpvS[tid] = NEG_INF; bnvS[tid] = NEG_INF;
        bpiS[tid] = 0x7FFFFFFF; bniS[tid] = 0x7FFFFFFF;
    }

    for (int jj = 0; jj < N / 128 / JSPLIT; ++jj) {
        const int j0 = (jsplit * (N / 128 / JSPLIT) + jj) * 128;

        f32x4 acc[4][4];
        #pragma unroll
        for (int mt = 0; mt < 4; ++mt)
            #pragma unroll
            for (int nt = 0; nt < 4; ++nt) acc[mt][nt] = (f32x4){0.f, 0.f, 0.f, 0.f};

        for (int dk = 0; dk < D; dk += 32) {
            __syncthreads();  // previous chunk's frag reads / state init done
            #pragma unroll
            for (int it = 0; it < 2; ++it) {
                const int s = it * 256 + tid;          // 16B slot id, 0..511
                const int r = s >> 2, ko = (s & 3) * 8;
                const int lbase = (it * 256 + w * 64) * 16;  // wave-uniform bytes
                const size_t ga = (size_t)(i0 + r) * D + dk + ko;
                const size_t gb = (size_t)(j0 + r) * D + dk + ko;
                gload16(qh + ga, (char*)Ah + lbase);
                gload16(ql + ga, (char*)Al + lbase);
                gload16(qh + gb, (char*)Bh + lbase);
                gload16(ql + gb, (char*)Bl + lbase);
            }
            __syncthreads();

            bf16x8 fah[4], fal[4], fbh[4], fbl[4];
            #pragma unroll
            for (int t = 0; t < 4; ++t) {
                const int ar = (wy * 64 + t * 16 + lc) * 32 + quad * 8;
                const int br = (wx * 64 + t * 16 + lc) * 32 + quad * 8;
                fah[t] = *(const bf16x8*)&Ah[ar];
                fal[t] = *(const bf16x8*)&Al[ar];
                fbh[t] = *(const bf16x8*)&Bh[br];
                fbl[t] = *(const bf16x8*)&Bl[br];
            }
            #pragma unroll
            for (int mt = 0; mt < 4; ++mt)
                #pragma unroll
                for (int nt = 0; nt < 4; ++nt) {
                    acc[mt][nt] = __builtin_amdgcn_mfma_f32_16x16x32_bf16(
                        fah[mt], fbh[nt], acc[mt][nt], 0, 0, 0);
                    acc[mt][nt] = __builtin_amdgcn_mfma_f32_16x16x32_bf16(
                        fah[mt], fbl[nt], acc[mt][nt], 0, 0, 0);
                    acc[mt][nt] = __builtin_amdgcn_mfma_f32_16x16x32_bf16(
                        fal[mt], fbh[nt], acc[mt][nt], 0, 0, 0);
                }
        }

        // ---- epilogue for this 128x128 tile: masked argmax, exact
        // first-occurrence semantics (ascending col scan, strict >)
        float sqj[4]; int tj[4];
        #pragma unroll
        for (int nt = 0; nt < 4; ++nt) {
            const int col = j0 + wx * 64 + nt * 16 + lc;
            sqj[nt] = sqv[col]; tj[nt] = tgt[col];
        }
        #pragma unroll
        for (int mt = 0; mt < 4; ++mt) {
            #pragma unroll
            for (int reg = 0; reg < 4; ++reg) {
                const int sr = wy * 64 + mt * 16 + quad * 4 + reg;  // local row
                const int row = i0 + sr;
                const float si = sqv[row];
                const int ti = tgt[row];
                float bpv = NEG_INF, bnv = NEG_INF;
                int bpi = 0x7FFFFFFF, bni = 0x7FFFFFFF;
                #pragma unroll
                for (int nt = 0; nt < 4; ++nt) {
                    const int col = j0 + wx * 64 + nt * 16 + lc;
                    const float dist = fmaf(-2.0f, acc[mt][nt][reg], si + sqj[nt]);
                    const bool same = (ti == tj[nt]);
                    const bool dia = (row == col);
                    const float vp = dia ? NEG_INF : (same ? dist : 0.0f);
                    const float vn = dia ? NEG_INF : (same ? 0.0f : dist);
                    if (vp > bpv) { bpv = vp; bpi = col; }
                    if (vn > bnv) { bnv = vn; bni = col; }
                }
                #pragma unroll
                for (int off = 1; off < 16; off <<= 1) {  // within quad (16 lanes)
                    const float pv = __shfl_xor(bpv, off, 64);
                    const int   pi = __shfl_xor(bpi, off, 64);
                    if (pv > bpv || (pv == bpv && pi < bpi)) { bpv = pv; bpi = pi; }
                    const float nv = __shfl_xor(bnv, off, 64);
                    const int   ni = __shfl_xor(bni, off, 64);
                    if (nv > bnv || (nv == bnv && ni < bni)) { bnv = nv; bni = ni; }
                }
                if (lc == 0) {  // unique owner lane per row; no race, no barrier
                    if (bpv > bpvS[sr] || (bpv == bpvS[sr] && bpi < bpiS[sr])) {
                        bpvS[sr] = bpv; bpiS[sr] = bpi;
                    }
                    if (bnv > bnvS[sr] || (bnv == bnvS[sr] && bni < bniS[sr])) {
                        bnvS[sr] = bnv; bniS[sr] = bni;
                    }
                }
            }
        }
    }

    // final write: same owner lanes read their own LDS state
    #pragma unroll
    for (int mt = 0; mt < 4; ++mt)
        #pragma unroll
        for (int reg = 0; reg < 4; ++reg)
            if (lc == 0) {
                const int sr = wy * 64 + mt * 16 + quad * 4 + reg;
                const int row = i0 + sr;
                pos_val[jsplit * N + row] = bpvS[sr];
                pos_idx[jsplit * N + row] = bpiS[sr];
                neg_val[jsplit * N + row] = bnvS[sr];
                neg_idx[jsplit * N + row] = bniS[sr];
            }
}

// ---------------------------------------------------------------- kernel 2
// Merge split partials (ascending split = ascending idx), recompute exact
// fp32 distances like the reference, fused mean via one atomicAdd per block.
__global__ __launch_bounds__(256) void finalize_kernel(
    const float* __restrict__ q,
    const float* __restrict__ pos_val, const int* __restrict__ pos_idx,
    const float* __restrict__ neg_val, const int* __restrict__ neg_idx,
    float* __restrict__ out)
{
    __shared__ float red[4];
    const int wv = threadIdx.x >> 6;
    const int row = blockIdx.x * 4 + wv;
    const int lane = threadIdx.x & 63;

    float bpv = NEG_INF, bnv = NEG_INF;
    int bpi = 0x7FFFFFFF, bni = 0x7FFFFFFF;
    #pragma unroll
    for (int s = 0; s < JSPLIT; ++s) {
        float v = pos_val[s * N + row]; int ix = pos_idx[s * N + row];
        if (v > bpv || (v == bpv && ix < bpi)) { bpv = v; bpi = ix; }
        v = neg_val[s * N + row]; ix = neg_idx[s * N + row];
        if (v > bnv || (v == bnv && ix < bni)) { bnv = v; bni = ix; }
    }

    const float4 qi = ((const float4*)(q + row * D))[lane];
    const float4 qp = ((const float4*)(q + bpi * D))[lane];
    const float4 qn = ((const float4*)(q + bni * D))[lane];
    float dx, dp = 0.0f, dn = 0.0f;
    dx = qi.x - qp.x; dp += dx * dx;
    dx = qi.y - qp.y; dp += dx * dx;
    dx = qi.z - qp.z; dp += dx * dx;
    dx = qi.w - qp.w; dp += dx * dx;
    dx = qi.x - qn.x; dn += dx * dx;
    dx = qi.y - qn.y; dn += dx * dx;
    dx = qi.z - qn.z; dn += dx * dx;
    dx = qi.w - qn.w; dn += dx * dx;
    #pragma unroll
    for (int off = 32; off; off >>= 1) {
        dp += __shfl_down(dp, off, 64);
        dn += __shfl_down(dn, off, 64);
    }
    if (lane == 0) red[wv] = fmaxf(0.0f, (1.0f - dp) + dn);
    __syncthreads();
    if (threadIdx.x == 0)
        atomicAdd(out, (red[0] + red[1] + red[2] + red[3]) * (1.0f / N));
}

// ----------------------------------------------------------------
extern "C" void kernel_launch(void* const* d_in, const int* in_sizes, int n_in,
                              void* d_out, int out_size, void* d_ws, size_t ws_size,
                              hipStream_t stream) {
    const float* q = (const float*)d_in[0];
    const int* tgt = (const int*)d_in[1];
    float* out = (float*)d_out;

    // ws layout (~10.3 MB)
    unsigned short* qh = (unsigned short*)d_ws;     // N*D bf16 bits
    unsigned short* ql = qh + (size_t)N * D;        // N*D
    float* sqv     = (float*)(ql + (size_t)N * D);  // N
    float* pos_val = sqv + N;                       // JSPLIT*N
    float* neg_val = pos_val + JSPLIT * N;          // JSPLIT*N
    int*   pos_idx = (int*)(neg_val + JSPLIT * N);  // JSPLIT*N
    int*   neg_idx = pos_idx + JSPLIT * N;          // JSPLIT*N

    hipMemsetAsync(out, 0, sizeof(float), stream);
    prep_kernel<<<dim3(N / 4), dim3(256), 0, stream>>>(q, qh, ql, sqv);
    mine_kernel<<<dim3(N / 128, JSPLIT), dim3(256), 0, stream>>>(
        qh, ql, tgt, sqv, pos_val, pos_idx, neg_val, neg_idx);
    finalize_kernel<<<dim3(N / 4), dim3(256), 0, stream>>>(
        q, pos_val, pos_idx, neg_val, neg_idx, out);
}